// Round 9
// baseline (11847.599 us; speedup 1.0000x reference)
//
#include <hip/hip_runtime.h>
#include <cmath>

namespace {

constexpr int BATCH = 64;
constexpr int NREG  = 49;
constexpr int FEATN = 2048;
constexpr int FHN   = 512;
constexpr int HID   = 512;
constexpr int EMBN  = 512;
constexpr int VOC   = 32000;
constexpr int TSTEPS= 40;
constexpr int G4    = 2048;       // 4*H
constexpr int NVT   = VOC / 128;  // 250 v-tiles for logits
constexpr int NBLK  = 256;        // persistent grid (1 block/CU)
constexpr int NLSTM = 128;        // blocks doing LSTM phases
constexpr int NTHR  = 512;        // 8 waves/block

typedef short bf16x8 __attribute__((ext_vector_type(8)));
typedef float f32x4  __attribute__((ext_vector_type(4)));

__device__ __forceinline__ float sigm(float x) { return 1.0f / (1.0f + expf(-x)); }

__device__ __forceinline__ unsigned short f2bf(float f) {
  unsigned u = __float_as_uint(f);
  unsigned r = (u + 0x7fffu + ((u >> 16) & 1u)) >> 16;   // RNE
  return (unsigned short)r;
}
__device__ __forceinline__ float bf2f(unsigned short h) {
  return __uint_as_float(((unsigned)h) << 16);
}
// anti-rematerialization: value becomes asm-produced; compiler must keep it live
__device__ __forceinline__ void pin(bf16x8& v) { asm volatile("" : "+v"(v)); }

__device__ __forceinline__ bool better(float a, int ia, float b, int ib) {
  return a > b || (a == b && ia < ib);
}
__device__ __forceinline__ void top2_merge(float& v1, int& i1, float& v2, int& i2,
                                           float u1, int j1, float u2, int j2) {
  if (better(u1, j1, v1, i1)) {
    float t = v1; int ti = i1;
    v1 = u1; i1 = j1;
    if (better(u2, j2, t, ti)) { v2 = u2; i2 = j2; } else { v2 = t; i2 = ti; }
  } else {
    if (better(u1, j1, v2, i2)) { v2 = u1; i2 = j1; }
  }
}
__device__ __forceinline__ void lse_merge(float& m, float& s, float om, float os) {
  float nm = fmaxf(m, om);
  float ns = 0.f;
  if (m  > -INFINITY) ns += s  * expf(m  - nm);
  if (om > -INFINITY) ns += os * expf(om - nm);
  m = nm; s = ns;
}

// ================= shared memory: persistent emb tile + phase union =================
struct Smem {
  unsigned short embl[128 * 512];            // 128KB, XOR-swizzled, PERSISTENT all 40 steps
  union {
    float gs[4][64][16];                     // LSTM K-split partials [ksl][batch][row16] 16KB
    struct {                                 // phase C reduction (12KB)
      float rm[512], rs[512], rv1[512], rv2[512];
      int   ri1[512], ri2[512];
    } c;
    struct {                                 // phase D (10KB)
      float rm[256], rs[256], rv1[256], rv2[256];
      int   ri1[256], ri2[256];
      float s1[512], s2[512];
    } d;
  } u;
};                                           // 147456 B -> 1 block/CU

// ================= dataflow sync: monotonic counter + 8-way replicated epoch =================
struct Sync {
  unsigned cnt;        // producers fetch_add here (monotonic across steps)
  unsigned pad0[31];
  unsigned rep[8][32]; // finishing producer publishes step number to 8 lines
};                      // 1152 B

// producer: data writes -> fence -> fetch_add; the one completing the step publishes
__device__ __forceinline__ void produce(Sync* s, unsigned need, unsigned stepval) {
  __syncthreads();
  if (threadIdx.x == 0) {
    __threadfence();
    unsigned old = __hip_atomic_fetch_add(&s->cnt, 1u, __ATOMIC_ACQ_REL, __HIP_MEMORY_SCOPE_AGENT);
    if (old == need - 1u) {
#pragma unroll
      for (int r = 0; r < 8; ++r)
        __hip_atomic_store(&s->rep[r][0], stepval, __ATOMIC_RELEASE, __HIP_MEMORY_SCOPE_AGENT);
    }
  }
}
// consumer: spin on own replica until step reached
__device__ __forceinline__ void consume(Sync* s, unsigned stepval, int blk) {
  if (threadIdx.x == 0) {
    while (__hip_atomic_load(&s->rep[blk & 7][0], __ATOMIC_ACQUIRE, __HIP_MEMORY_SCOPE_AGENT) < stepval)
      __builtin_amdgcn_s_sleep(1);
    __threadfence();
  }
  __syncthreads();
}

// ================= prep kernels (one-time, unchanged) =================

__global__ __launch_bounds__(256) void k_trans(const float* __restrict__ src,
    unsigned short* __restrict__ dhi, unsigned short* __restrict__ dlo, int K, int N) {
  __shared__ float tile[32][33];
  const int k0 = blockIdx.x * 32, n0 = blockIdx.y * 32;
  const int tx = threadIdx.x & 31, ty = threadIdx.x >> 5;
#pragma unroll
  for (int r = ty; r < 32; r += 8) tile[r][tx] = src[(size_t)(k0 + r) * N + n0 + tx];
  __syncthreads();
#pragma unroll
  for (int r = ty; r < 32; r += 8) {
    float v = tile[tx][r];
    unsigned short hv = f2bf(v);
    size_t o = (size_t)(n0 + r) * K + k0 + tx;
    dhi[o] = hv;
    dlo[o] = f2bf(v - bf2f(hv));
  }
}

__global__ void k_split(const float* __restrict__ src, unsigned short* __restrict__ dhi,
                        unsigned short* __restrict__ dlo) {
  const size_t i = (size_t)blockIdx.x * 256 + threadIdx.x;
  const float4* p = reinterpret_cast<const float4*>(src) + i * 2;
  float4 a = p[0], b = p[1];
  float v[8] = {a.x, a.y, a.z, a.w, b.x, b.y, b.z, b.w};
  unsigned short hi[8], lo[8];
#pragma unroll
  for (int j = 0; j < 8; ++j) {
    hi[j] = f2bf(v[j]);
    lo[j] = f2bf(v[j] - bf2f(hi[j]));
  }
  uint4 oh, ol;
  oh.x = hi[0] | (hi[1] << 16); oh.y = hi[2] | (hi[3] << 16);
  oh.z = hi[4] | (hi[5] << 16); oh.w = hi[6] | (hi[7] << 16);
  ol.x = lo[0] | (lo[1] << 16); ol.y = lo[2] | (lo[3] << 16);
  ol.z = lo[4] | (lo[5] << 16); ol.w = lo[6] | (lo[7] << 16);
  reinterpret_cast<uint4*>(dhi)[i] = oh;
  reinterpret_cast<uint4*>(dlo)[i] = ol;
}

__global__ void k_emb2bf(const float* __restrict__ emb, unsigned short* __restrict__ ebf) {
  const size_t i = (size_t)blockIdx.x * 256 + threadIdx.x;
  const float4* p = reinterpret_cast<const float4*>(emb) + i * 2;
  float4 a = p[0], b = p[1];
  uint4 o;
  o.x = (unsigned)f2bf(a.x) | ((unsigned)f2bf(a.y) << 16);
  o.y = (unsigned)f2bf(a.z) | ((unsigned)f2bf(a.w) << 16);
  o.z = (unsigned)f2bf(b.x) | ((unsigned)f2bf(b.y) << 16);
  o.w = (unsigned)f2bf(b.z) | ((unsigned)f2bf(b.w) << 16);
  reinterpret_cast<uint4*>(ebf)[i] = o;
}

__global__ __launch_bounds__(256) void k_feat_mfma(
    const unsigned short* __restrict__ Ahi, const unsigned short* __restrict__ Alo,
    const unsigned short* __restrict__ Bhi, const unsigned short* __restrict__ Blo,
    const float* __restrict__ bias, float* __restrict__ femb) {
  const int m0 = blockIdx.x * 64, n0 = blockIdx.y * 64;
  const int tid = threadIdx.x, lane = tid & 63, w = tid >> 6;
  const int l15 = lane & 15, l4 = lane >> 4;
  f32x4 acc[4];
#pragma unroll
  for (int nt = 0; nt < 4; ++nt) acc[nt] = (f32x4){0.f, 0.f, 0.f, 0.f};
  const size_t arow = (size_t)(m0 + w * 16 + l15) * FEATN;
  for (int kk = 0; kk < FEATN / 32; ++kk) {
    const int k = kk * 32 + l4 * 8;
    bf16x8 a1 = *reinterpret_cast<const bf16x8*>(Ahi + arow + k);
    bf16x8 a2 = *reinterpret_cast<const bf16x8*>(Alo + arow + k);
#pragma unroll
    for (int nt = 0; nt < 4; ++nt) {
      const size_t brow = (size_t)(n0 + nt * 16 + l15) * FEATN + k;
      bf16x8 b1 = *reinterpret_cast<const bf16x8*>(Bhi + brow);
      bf16x8 b2 = *reinterpret_cast<const bf16x8*>(Blo + brow);
      acc[nt] = __builtin_amdgcn_mfma_f32_16x16x32_bf16(a1, b1, acc[nt], 0, 0, 0);
      acc[nt] = __builtin_amdgcn_mfma_f32_16x16x32_bf16(a1, b2, acc[nt], 0, 0, 0);
      acc[nt] = __builtin_amdgcn_mfma_f32_16x16x32_bf16(a2, b1, acc[nt], 0, 0, 0);
    }
  }
#pragma unroll
  for (int nt = 0; nt < 4; ++nt)
#pragma unroll
    for (int i = 0; i < 4; ++i) {
      int m = m0 + w * 16 + l4 * 4 + i, n = n0 + nt * 16 + l15;
      femb[(size_t)m * FHN + n] = tanhf(acc[nt][i] + bias[n]);
    }
}

__global__ void k_mean(const float* __restrict__ femb, float* __restrict__ fmean) {
  const int gid = blockIdx.x * 256 + threadIdx.x;  // 32768
  const int b = gid >> 9, f = gid & 511;
  float s = 0.f;
  for (int n = 0; n < NREG; ++n) s += femb[(size_t)(b * NREG + n) * FHN + f];
  fmean[gid] = s * (1.0f / NREG);
}

__global__ __launch_bounds__(256) void k_h0c0(const float* __restrict__ fmean,
    const float* __restrict__ Wc, const float* __restrict__ bc,
    const float* __restrict__ Wh, const float* __restrict__ bh,
    float* __restrict__ hbuf, float* __restrict__ cbuf,
    unsigned short* __restrict__ hshi, unsigned short* __restrict__ hslo) {
  const int n0 = blockIdx.x * 64, l = blockIdx.y, isH = blockIdx.z;
  const float* W   = (isH ? Wh : Wc) + (size_t)l * FHN * HID;
  const float* bias= (isH ? bh : bc) + l * HID;
  float* outp      = (isH ? hbuf : cbuf) + (size_t)l * BATCH * HID;
  __shared__ float As[16][68], Bs[16][68];
  const int tid = threadIdx.x, tx = tid & 15, ty = tid >> 4;
  float acc[4][4] = {};
  for (int k0 = 0; k0 < FHN; k0 += 16) {
#pragma unroll
    for (int e = 0; e < 4; ++e) { int idx = tid + e * 256, m = idx >> 4, k = idx & 15; As[k][m] = fmean[m * FHN + k0 + k]; }
#pragma unroll
    for (int e = 0; e < 4; ++e) { int idx = tid + e * 256, k = idx >> 6, n = idx & 63; Bs[k][n] = W[(size_t)(k0 + k) * HID + n0 + n]; }
    __syncthreads();
#pragma unroll
    for (int k = 0; k < 16; ++k) {
      float4 av = *(const float4*)&As[k][ty * 4];
      float4 bv = *(const float4*)&Bs[k][tx * 4];
      float a[4] = {av.x, av.y, av.z, av.w}, b[4] = {bv.x, bv.y, bv.z, bv.w};
#pragma unroll
      for (int i = 0; i < 4; ++i)
#pragma unroll
        for (int j = 0; j < 4; ++j) acc[i][j] = fmaf(a[i], b[j], acc[i][j]);
    }
    __syncthreads();
  }
#pragma unroll
  for (int i = 0; i < 4; ++i) {
    int m = ty * 4 + i, n = n0 + tx * 4;
    float vals[4];
#pragma unroll
    for (int j = 0; j < 4; ++j) vals[j] = acc[i][j] + bias[n + j];
    *(float4*)&outp[(size_t)m * HID + n] = make_float4(vals[0], vals[1], vals[2], vals[3]);
    if (isH) {
#pragma unroll
      for (int j = 0; j < 4; ++j) {
        unsigned short hv = f2bf(vals[j]);
        size_t o = (size_t)l * BATCH * HID + (size_t)m * HID + n + j;  // parity-0 slot
        hshi[o] = hv;
        hslo[o] = f2bf(vals[j] - bf2f(hv));
      }
    }
  }
}

__global__ void k_initx(unsigned short* __restrict__ xhi, unsigned short* __restrict__ xlo) {
  const int i = blockIdx.x * 256 + threadIdx.x;
  xhi[i] = 0x4040; xlo[i] = 0;      // 3.0 exact in bf16 (parity-0 x buffer)
}

__global__ void k_zero(unsigned* __restrict__ bar) {
  bar[blockIdx.x * 256 + threadIdx.x] = 0;   // 2048 uints
}

// ================= persistent-kernel phase bodies (identical math to r8) =================

__device__ __forceinline__ void lstm_phase(
    const bf16x8 (&wl)[2][2][4],            // [mat(x/h)][part(hi/lo)][ks] for this layer
    int blk, int tid, int half, int ksl, int l,
    const unsigned short* __restrict__ xh, const unsigned short* __restrict__ xl,
    const unsigned short* __restrict__ hh, const unsigned short* __restrict__ hl,
    const float* __restrict__ bl_,
    float* __restrict__ hbuf, float* __restrict__ cbuf,
    unsigned short* __restrict__ ho_hi, unsigned short* __restrict__ ho_lo,
    Smem& sm) {
  const int lane = tid & 63;
  const int l15 = lane & 15, l4 = lane >> 4;
  f32x4 acc0 = (f32x4){0.f, 0.f, 0.f, 0.f};
  f32x4 acc1 = (f32x4){0.f, 0.f, 0.f, 0.f};
  const size_t ar0 = (size_t)(half * 32 + l15) * 512 + ksl * 128 + l4 * 8;
  const size_t ar1 = ar0 + 16 * 512;
#pragma unroll
  for (int ks = 0; ks < 4; ++ks) {           // x @ Wih (3-term bf16 split)
    bf16x8 a1 = *reinterpret_cast<const bf16x8*>(xh + ar0 + ks * 32);
    bf16x8 a2 = *reinterpret_cast<const bf16x8*>(xl + ar0 + ks * 32);
    acc0 = __builtin_amdgcn_mfma_f32_16x16x32_bf16(a1, wl[0][0][ks], acc0, 0, 0, 0);
    acc0 = __builtin_amdgcn_mfma_f32_16x16x32_bf16(a1, wl[0][1][ks], acc0, 0, 0, 0);
    acc0 = __builtin_amdgcn_mfma_f32_16x16x32_bf16(a2, wl[0][0][ks], acc0, 0, 0, 0);
    bf16x8 c1 = *reinterpret_cast<const bf16x8*>(xh + ar1 + ks * 32);
    bf16x8 c2 = *reinterpret_cast<const bf16x8*>(xl + ar1 + ks * 32);
    acc1 = __builtin_amdgcn_mfma_f32_16x16x32_bf16(c1, wl[0][0][ks], acc1, 0, 0, 0);
    acc1 = __builtin_amdgcn_mfma_f32_16x16x32_bf16(c1, wl[0][1][ks], acc1, 0, 0, 0);
    acc1 = __builtin_amdgcn_mfma_f32_16x16x32_bf16(c2, wl[0][0][ks], acc1, 0, 0, 0);
  }
#pragma unroll
  for (int ks = 0; ks < 4; ++ks) {           // h @ Whh
    bf16x8 a1 = *reinterpret_cast<const bf16x8*>(hh + ar0 + ks * 32);
    bf16x8 a2 = *reinterpret_cast<const bf16x8*>(hl + ar0 + ks * 32);
    acc0 = __builtin_amdgcn_mfma_f32_16x16x32_bf16(a1, wl[1][0][ks], acc0, 0, 0, 0);
    acc0 = __builtin_amdgcn_mfma_f32_16x16x32_bf16(a1, wl[1][1][ks], acc0, 0, 0, 0);
    acc0 = __builtin_amdgcn_mfma_f32_16x16x32_bf16(a2, wl[1][0][ks], acc0, 0, 0, 0);
    bf16x8 c1 = *reinterpret_cast<const bf16x8*>(hh + ar1 + ks * 32);
    bf16x8 c2 = *reinterpret_cast<const bf16x8*>(hl + ar1 + ks * 32);
    acc1 = __builtin_amdgcn_mfma_f32_16x16x32_bf16(c1, wl[1][0][ks], acc1, 0, 0, 0);
    acc1 = __builtin_amdgcn_mfma_f32_16x16x32_bf16(c1, wl[1][1][ks], acc1, 0, 0, 0);
    acc1 = __builtin_amdgcn_mfma_f32_16x16x32_bf16(c2, wl[1][0][ks], acc1, 0, 0, 0);
  }
#pragma unroll
  for (int i = 0; i < 4; ++i) {
    sm.u.gs[ksl][half * 32 + l4 * 4 + i][l15] = acc0[i];
    sm.u.gs[ksl][half * 32 + 16 + l4 * 4 + i][l15] = acc1[i];
  }
  __syncthreads();
  if (tid < 256) {                           // cell: 64 batches x 4 cols
    const int b = tid >> 2, c = tid & 3, j = blk * 4 + c;
    float g0 = 0.f, g1 = 0.f, g2 = 0.f, g3 = 0.f;
#pragma unroll
    for (int k2 = 0; k2 < 4; ++k2) {
      g0 += sm.u.gs[k2][b][c];
      g1 += sm.u.gs[k2][b][4 + c];
      g2 += sm.u.gs[k2][b][8 + c];
      g3 += sm.u.gs[k2][b][12 + c];
    }
    g0 += bl_[l * 2048 + j];
    g1 += bl_[l * 2048 + 512 + j];
    g2 += bl_[l * 2048 + 1024 + j];
    g3 += bl_[l * 2048 + 1536 + j];
    const size_t o = (size_t)l * BATCH * HID + (size_t)b * HID + j;
    float cn = sigm(g1) * cbuf[o] + sigm(g0) * tanhf(g2);
    float hn = sigm(g3) * tanhf(cn);
    cbuf[o] = cn; hbuf[o] = hn;
    unsigned short hv = f2bf(hn);
    ho_hi[b * HID + j] = hv; ho_lo[b * HID + j] = f2bf(hn - bf2f(hv));
  }
  __syncthreads();
}

__device__ __forceinline__ void logits_block(int blk, int tid,
    const unsigned short* __restrict__ h1hi,
    const float4 gc0, const float4 gc1, const float4 gc2, const float4 gc3,
    float* __restrict__ red, Smem& sm) {
  const int v0 = blk * 128;
  const int lane = tid & 63, w = tid >> 6;
  const int l15 = lane & 15, l4 = lane >> 4;
  const int arow = w * 16 + l15;
  const char* abase = reinterpret_cast<const char*>(sm.embl) + arow * 1024;
  const int axor = (arow & 7) << 4;

  f32x4 acc[4];
#pragma unroll
  for (int cb = 0; cb < 4; ++cb) acc[cb] = (f32x4){0.f, 0.f, 0.f, 0.f};
#pragma unroll
  for (int ks = 0; ks < 16; ++ks) {
    bf16x8 a0 = *reinterpret_cast<const bf16x8*>(abase + ((ks * 64 + l4 * 16) ^ axor));
#pragma unroll
    for (int cb = 0; cb < 4; ++cb) {
      const int brow = cb * 16 + l15;
      bf16x8 bb = *reinterpret_cast<const bf16x8*>(h1hi + (size_t)brow * 512 + ks * 32 + l4 * 8);
      acc[cb] = __builtin_amdgcn_mfma_f32_16x16x32_bf16(a0, bb, acc[cb], 0, 0, 0);
    }
  }

  const int vb = v0 + w * 16 + l4 * 4;
#pragma unroll
  for (int cb = 0; cb < 4; ++cb) {
    const float4 g0 = (cb == 0) ? gc0 : (cb == 1) ? gc1 : (cb == 2) ? gc2 : gc3;
    float lg[4] = {acc[cb][0], acc[cb][1], acc[cb][2], acc[cb][3]};
    float gv[4] = {g0.x, g0.y, g0.z, g0.w};
    float mx = fmaxf(fmaxf(lg[0], lg[1]), fmaxf(lg[2], lg[3]));
    float ss = 0.f;
    float v1 = -INFINITY, v2 = -INFINITY; int i1 = 0x7fffffff, i2 = 0x7fffffff;
#pragma unroll
    for (int i = 0; i < 4; ++i) {
      ss += expf(lg[i] - mx);
      float val = lg[i] + gv[i];
      int idx = vb + i;
      if (better(val, idx, v1, i1)) { v2 = v1; i2 = i1; v1 = val; i1 = idx; }
      else if (better(val, idx, v2, i2)) { v2 = val; i2 = idx; }
    }
#pragma unroll
    for (int mask = 16; mask <= 32; mask <<= 1) {
      float om = __shfl_xor(mx, mask);
      float os = __shfl_xor(ss, mask);
      float u1 = __shfl_xor(v1, mask); int j1 = __shfl_xor(i1, mask);
      float u2 = __shfl_xor(v2, mask); int j2 = __shfl_xor(i2, mask);
      lse_merge(mx, ss, om, os);
      top2_merge(v1, i1, v2, i2, u1, j1, u2, j2);
    }
    if (lane < 16) {
      int slot = (w * 4 + cb) * 16 + l15;
      sm.u.c.rm[slot] = mx; sm.u.c.rs[slot] = ss;
      sm.u.c.rv1[slot] = v1; sm.u.c.ri1[slot] = i1; sm.u.c.rv2[slot] = v2; sm.u.c.ri2[slot] = i2;
    }
  }
  __syncthreads();
  if (tid < 64) {
    const int b = tid, cb = b >> 4, c = b & 15;
    int s0 = cb * 16 + c;                        // vsub = 0
    float M = sm.u.c.rm[s0], S = sm.u.c.rs[s0], V1 = sm.u.c.rv1[s0], V2 = sm.u.c.rv2[s0];
    int I1 = sm.u.c.ri1[s0], I2 = sm.u.c.ri2[s0];
#pragma unroll
    for (int vs = 1; vs < 8; ++vs) {
      int sl = (vs * 4 + cb) * 16 + c;
      lse_merge(M, S, sm.u.c.rm[sl], sm.u.c.rs[sl]);
      top2_merge(V1, I1, V2, I2, sm.u.c.rv1[sl], sm.u.c.ri1[sl], sm.u.c.rv2[sl], sm.u.c.ri2[sl]);
    }
    float* rp = red + ((size_t)blk * 64 + tid) * 8;
    rp[0] = M; rp[1] = S;
    rp[2] = V1; rp[3] = __int_as_float(I1);
    rp[4] = V2; rp[5] = __int_as_float(I2);
  }
  __syncthreads();
}

__device__ __forceinline__ void sample_block(int b, int tid, int t,
    const float* __restrict__ red, const float* __restrict__ emb,
    const float* __restrict__ h1f, const float* __restrict__ gum_t,
    unsigned short* __restrict__ xhi, unsigned short* __restrict__ xlo,
    float* __restrict__ out, Smem& sm) {
  if (tid < 256) {
    float m = -INFINITY, s = 0.f, v1 = -INFINITY, v2 = -INFINITY;
    int i1 = 0x7fffffff, i2 = 0x7fffffff;
    if (tid < NVT) {
      const float* rp = red + ((size_t)tid * 64 + b) * 8;
      m = rp[0]; s = rp[1];
      v1 = rp[2]; i1 = __float_as_int(rp[3]);
      v2 = rp[4]; i2 = __float_as_int(rp[5]);
    }
    sm.u.d.rm[tid] = m; sm.u.d.rs[tid] = s;
    sm.u.d.rv1[tid] = v1; sm.u.d.ri1[tid] = i1; sm.u.d.rv2[tid] = v2; sm.u.d.ri2[tid] = i2;
  }
  __syncthreads();
  for (int off = 128; off > 0; off >>= 1) {
    if (tid < off) {
      float M = sm.u.d.rm[tid], S = sm.u.d.rs[tid];
      lse_merge(M, S, sm.u.d.rm[tid + off], sm.u.d.rs[tid + off]);
      sm.u.d.rm[tid] = M; sm.u.d.rs[tid] = S;
      float a1 = sm.u.d.rv1[tid], a2 = sm.u.d.rv2[tid]; int c1 = sm.u.d.ri1[tid], c2 = sm.u.d.ri2[tid];
      top2_merge(a1, c1, a2, c2, sm.u.d.rv1[tid + off], sm.u.d.ri1[tid + off],
                 sm.u.d.rv2[tid + off], sm.u.d.ri2[tid + off]);
      sm.u.d.rv1[tid] = a1; sm.u.d.ri1[tid] = c1; sm.u.d.rv2[tid] = a2; sm.u.d.ri2[tid] = c2;
    }
    __syncthreads();
  }
  const int I1 = sm.u.d.ri1[0], I2 = sm.u.d.ri2[0];
  const float lse = sm.u.d.rm[0] + logf(sm.u.d.rs[0]);
  const float* e1 = emb + (size_t)I1 * EMBN;
  const float* e2 = emb + (size_t)I2 * EMBN;
  const float* hb = h1f + b * EMBN;
  {
    float hv = hb[tid];
    sm.u.d.s1[tid] = e1[tid] * hv;
    sm.u.d.s2[tid] = e2[tid] * hv;
  }
  __syncthreads();
  for (int off = 256; off > 0; off >>= 1) {
    if (tid < off) { sm.u.d.s1[tid] += sm.u.d.s1[tid + off]; sm.u.d.s2[tid] += sm.u.d.s2[tid + off]; }
    __syncthreads();
  }
  const float d1 = sm.u.d.s1[0], d2 = sm.u.d.s2[0];
  const float x1 = d1 + gum_t[(size_t)b * VOC + I1];
  const float x2 = d2 + gum_t[(size_t)b * VOC + I2];
  int tok; float dsel;
  if (x2 > x1 || (x2 == x1 && I2 < I1)) { tok = I2; dsel = d2; }
  else                                  { tok = I1; dsel = d1; }
  {
    float ev = emb[(size_t)tok * EMBN + tid];
    unsigned short hv = f2bf(ev);
    xhi[b * EMBN + tid] = hv;
    xlo[b * EMBN + tid] = f2bf(ev - bf2f(hv));
  }
  if (tid == 0) {
    out[b * TSTEPS + t] = (float)tok;
    out[BATCH * TSTEPS + b * TSTEPS + t] = dsel - lse;
  }
  __syncthreads();
}

// ================= persistent decode kernel: dataflow-synced, 256 x 512 =================
__global__ __launch_bounds__(NTHR, 2) void k_persist(
    const unsigned short* __restrict__ embbf, const float* __restrict__ emb,
    const float* __restrict__ gum, const unsigned short* __restrict__ wg,
    const float* __restrict__ b_l, float* __restrict__ hbuf, float* __restrict__ cbuf,
    unsigned short* __restrict__ xhi, unsigned short* __restrict__ xlo,   // [2 parity][64*512]
    unsigned short* __restrict__ hshi, unsigned short* __restrict__ hslo,
    float* __restrict__ red,                                              // [2 parity][250*64*8]
    float* __restrict__ out, unsigned* __restrict__ bar) {
  __shared__ Smem sm;
  const int blk = blockIdx.x, tid = threadIdx.x;
  if (blk >= NVT) return;                  // blocks 250-255: no role
  const size_t HS = (size_t)BATCH * HID;
  const size_t XS = (size_t)BATCH * EMBN;  // x parity stride
  const size_t RS = (size_t)NVT * 64 * 8;  // red parity stride
  const int lane = tid & 63, w = tid >> 6;
  const int l15 = lane & 15, l4 = lane >> 4;
  const int ksl = w & 3, half = w >> 2;
  const size_t WGM = (size_t)G4 * 512;
  const bool isL = blk < NLSTM;
  const bool isD = blk >= NLSTM && blk < NLSTM + BATCH;

  Sync* sA = reinterpret_cast<Sync*>(bar);
  Sync* sB = sA + 1;
  Sync* sC = sA + 2;
  Sync* sD = sA + 3;

  // ---- one-time: pin LSTM weight slice in registers ----
  bf16x8 wr[2][2][2][4];
  if (isL) {
    const int wrow = (l15 >> 2) * 512 + blk * 4 + (l15 & 3);
#pragma unroll
    for (int l = 0; l < 2; ++l)
#pragma unroll
      for (int m = 0; m < 2; ++m)
#pragma unroll
        for (int p = 0; p < 2; ++p) {
          const unsigned short* base = wg + (((size_t)l * 2 + m) * 2 + p) * WGM
                                          + (size_t)wrow * 512 + ksl * 128 + l4 * 8;
#pragma unroll
          for (int ks = 0; ks < 4; ++ks) {
            wr[l][m][p][ks] = *reinterpret_cast<const bf16x8*>(base + ks * 32);
            pin(wr[l][m][p][ks]);
          }
        }
  }

  // ---- one-time: stage emb v-tile into LDS (persistent, XOR-swizzled) ----
  {
    const uint4* ep = reinterpret_cast<const uint4*>(embbf + (size_t)blk * 128 * 512);
#pragma unroll
    for (int i = 0; i < 16; ++i) {
      int c = tid + i * NTHR;
      int row = c >> 6;
      int inb = (c & 63) << 4;
      uint4 v = ep[c];
      int sw = inb ^ ((row & 7) << 4);
      *reinterpret_cast<uint4*>(reinterpret_cast<char*>(sm.embl) + row * 1024 + sw) = v;
    }
  }
  __syncthreads();

  for (int t = 0; t < TSTEPS; ++t) {
    const float* gum_t = gum + (size_t)t * BATCH * VOC;
    const int p = t & 1, q = p ^ 1;
    const unsigned sv = (unsigned)(t + 1);

    // preload this thread's phase-C gumbel values (issued before any wait)
    float4 gc0, gc1, gc2, gc3;
    {
      const int vb_ = blk * 128 + w * 16 + l4 * 4;
      gc0 = *reinterpret_cast<const float4*>(gum_t + (size_t)(0 * 16 + l15) * VOC + vb_);
      gc1 = *reinterpret_cast<const float4*>(gum_t + (size_t)(1 * 16 + l15) * VOC + vb_);
      gc2 = *reinterpret_cast<const float4*>(gum_t + (size_t)(2 * 16 + l15) * VOC + vb_);
      gc3 = *reinterpret_cast<const float4*>(gum_t + (size_t)(3 * 16 + l15) * VOC + vb_);
    }

    if (isL) {
      if (t) consume(sD, (unsigned)t, blk);            // x[t&1] ready (D of step t-1)
      lstm_phase(wr[0], blk, tid, half, ksl, 0,
                 xhi + (size_t)(t & 1) * XS, xlo + (size_t)(t & 1) * XS,
                 hshi + ((size_t)p * 2 + 0) * HS, hslo + ((size_t)p * 2 + 0) * HS,
                 b_l, hbuf, cbuf,
                 hshi + ((size_t)q * 2 + 0) * HS, hslo + ((size_t)q * 2 + 0) * HS, sm);
      produce(sA, 128u * sv, sv);
      consume(sA, sv, blk);                            // full h0[q] ready
      lstm_phase(wr[1], blk, tid, half, ksl, 1,
                 hshi + ((size_t)q * 2 + 0) * HS, hslo + ((size_t)q * 2 + 0) * HS,
                 hshi + ((size_t)p * 2 + 1) * HS, hslo + ((size_t)p * 2 + 1) * HS,
                 b_l, hbuf, cbuf,
                 hshi + ((size_t)q * 2 + 1) * HS, hslo + ((size_t)q * 2 + 1) * HS, sm);
      produce(sB, 128u * sv, sv);
    }
    // phase C (all blocks 0..249)
    consume(sB, sv, blk);                              // h1[q] ready
    logits_block(blk, tid, hshi + ((size_t)q * 2 + 1) * HS, gc0, gc1, gc2, gc3,
                 red + (size_t)(t & 1) * RS, sm);
    produce(sC, 250u * sv, sv);
    // phase D (blocks 128..191)
    if (isD) {
      consume(sC, sv, blk);                            // all red partials ready
      sample_block(blk - NLSTM, tid, t, red + (size_t)(t & 1) * RS, emb, hbuf + HS, gum_t,
                   xhi + (size_t)((t + 1) & 1) * XS, xlo + (size_t)((t + 1) & 1) * XS, out, sm);
      produce(sD, 64u * sv, sv);
    }
  }
}

}  // namespace

extern "C" void kernel_launch(void* const* d_in, const int* in_sizes, int n_in,
                              void* d_out, int out_size, void* d_ws, size_t ws_size,
                              hipStream_t stream) {
  const float* img  = (const float*)d_in[0];
  const float* W_fh = (const float*)d_in[1];
  const float* b_fh = (const float*)d_in[2];
  const float* Wc   = (const float*)d_in[3];
  const float* bc   = (const float*)d_in[4];
  const float* Wh   = (const float*)d_in[5];
  const float* bh   = (const float*)d_in[6];
  const float* W_ih = (const float*)d_in[7];
  const float* W_hh = (const float*)d_in[8];
  const float* b_l  = (const float*)d_in[9];
  const float* emb  = (const float*)d_in[10];
  const float* gum  = (const float*)d_in[11];
  float* out = (float*)d_out;

  float* w     = (float*)d_ws;
  float* femb  = w;                                    // 3136*512
  float* fmean = femb + (size_t)3136 * 512;            // 64*512
  float* hbuf  = fmean + 64 * 512;                     // 2*64*512 f32
  float* cbuf  = hbuf + 2 * 64 * 512;                  // 2*64*512 f32
  float* red   = cbuf + 2 * 64 * 512;                  // [2][250*64*8]
  unsigned* bar = (unsigned*)(red + (size_t)2 * 250 * 64 * 8);   // 2048 uints (Sync[4])

  unsigned short* us = (unsigned short*)(bar + 2048);
  unsigned short* embbf  = us;                                  // 32000*512
  unsigned short* imghi  = embbf + (size_t)VOC * EMBN;          // 3136*2048
  unsigned short* imglo  = imghi + (size_t)3136 * 2048;
  unsigned short* wfh_hi = imglo + (size_t)3136 * 2048;         // 512*2048 (W_fh^T)
  unsigned short* wfh_lo = wfh_hi + (size_t)512 * 2048;
  unsigned short* wg     = wfh_lo + (size_t)512 * 2048;         // [l][mat][hi/lo][2048][512]
  const size_t WGM = (size_t)G4 * 512;
  unsigned short* xhi    = wg + 8 * WGM;                        // [2][64*512]
  unsigned short* xlo    = xhi + (size_t)2 * 64 * 512;
  unsigned short* hshi   = xlo + (size_t)2 * 64 * 512;          // [2 parity][2 layer][64][512]
  unsigned short* hslo   = hshi + (size_t)4 * 64 * 512;

  auto wgp = [&](int l, int mat, int part_) -> unsigned short* {
    return wg + (((size_t)l * 2 + mat) * 2 + part_) * WGM;
  };

  // ---- one-time prep ----
  k_emb2bf<<<8000, 256, 0, stream>>>(emb, embbf);
  k_split<<<3136 * 2048 / 8 / 256, 256, 0, stream>>>(img, imghi, imglo);
  k_trans<<<dim3(FEATN / 32, FHN / 32), 256, 0, stream>>>(W_fh, wfh_hi, wfh_lo, FEATN, FHN);
  for (int l = 0; l < 2; ++l) {
    k_trans<<<dim3(EMBN / 32, G4 / 32), 256, 0, stream>>>(W_ih + (size_t)l * EMBN * G4, wgp(l, 0, 0), wgp(l, 0, 1), EMBN, G4);
    k_trans<<<dim3(HID / 32, G4 / 32), 256, 0, stream>>>(W_hh + (size_t)l * HID * G4, wgp(l, 1, 0), wgp(l, 1, 1), HID, G4);
  }
  k_feat_mfma<<<dim3(49, 8), 256, 0, stream>>>(imghi, imglo, wfh_hi, wfh_lo, b_fh, femb);
  k_mean<<<128, 256, 0, stream>>>(femb, fmean);
  k_h0c0<<<dim3(8, 2, 2), 256, 0, stream>>>(fmean, Wc, bc, Wh, bh, hbuf, cbuf, hshi, hslo);
  k_initx<<<128, 256, 0, stream>>>(xhi, xlo);    // parity-0 x buffer
  k_zero<<<8, 256, 0, stream>>>(bar);

  // ---- persistent decode: dataflow counters instead of BSP barriers ----
  k_persist<<<NBLK, NTHR, 0, stream>>>(embbf, emb, gum, wg, b_l, hbuf, cbuf,
                                       xhi, xlo, hshi, hslo, red, out, bar);
}

// Round 11
// 5882.388 us; speedup vs baseline: 2.0141x; 2.0141x over previous
//
#include <hip/hip_runtime.h>
#include <cmath>

namespace {

constexpr int BATCH = 64;
constexpr int NREG  = 49;
constexpr int FEATN = 2048;
constexpr int FHN   = 512;
constexpr int HID   = 512;
constexpr int EMBN  = 512;
constexpr int VOC   = 32000;
constexpr int TSTEPS= 40;
constexpr int G4    = 2048;       // 4*H
constexpr int NVT   = VOC / 128;  // 250 v-tiles for logits

typedef short bf16x8 __attribute__((ext_vector_type(8)));
typedef float f32x4  __attribute__((ext_vector_type(4)));

__device__ __forceinline__ float sigm(float x) { return 1.0f / (1.0f + expf(-x)); }

__device__ __forceinline__ unsigned short f2bf(float f) {
  unsigned u = __float_as_uint(f);
  unsigned r = (u + 0x7fffu + ((u >> 16) & 1u)) >> 16;   // RNE
  return (unsigned short)r;
}
__device__ __forceinline__ float bf2f(unsigned short h) {
  return __uint_as_float(((unsigned)h) << 16);
}

// nontemporal loads via clang ext_vector types (float4/uint4 HIP structs are rejected)
__device__ __forceinline__ bf16x8 ntload_bf(const unsigned short* p) {
  return __builtin_nontemporal_load(reinterpret_cast<const bf16x8*>(p));
}
__device__ __forceinline__ f32x4 ntload_f4(const float* p) {
  return __builtin_nontemporal_load(reinterpret_cast<const f32x4*>(p));
}

__device__ __forceinline__ bool better(float a, int ia, float b, int ib) {
  return a > b || (a == b && ia < ib);
}
__device__ __forceinline__ void top2_merge(float& v1, int& i1, float& v2, int& i2,
                                           float u1, int j1, float u2, int j2) {
  if (better(u1, j1, v1, i1)) {
    float t = v1; int ti = i1;
    v1 = u1; i1 = j1;
    if (better(u2, j2, t, ti)) { v2 = u2; i2 = j2; } else { v2 = t; i2 = ti; }
  } else {
    if (better(u1, j1, v2, i2)) { v2 = u1; i2 = j1; }
  }
}
__device__ __forceinline__ void lse_merge(float& m, float& s, float om, float os) {
  float nm = fmaxf(m, om);
  float ns = 0.f;
  if (m  > -INFINITY) ns += s  * expf(m  - nm);
  if (om > -INFINITY) ns += os * expf(om - nm);
  m = nm; s = ns;
}

// ================= prep kernels (one-time, proven r3-r9) =================

__global__ __launch_bounds__(256) void k_trans(const float* __restrict__ src,
    unsigned short* __restrict__ dhi, unsigned short* __restrict__ dlo, int K, int N) {
  __shared__ float tile[32][33];
  const int k0 = blockIdx.x * 32, n0 = blockIdx.y * 32;
  const int tx = threadIdx.x & 31, ty = threadIdx.x >> 5;
#pragma unroll
  for (int r = ty; r < 32; r += 8) tile[r][tx] = src[(size_t)(k0 + r) * N + n0 + tx];
  __syncthreads();
#pragma unroll
  for (int r = ty; r < 32; r += 8) {
    float v = tile[tx][r];
    unsigned short hv = f2bf(v);
    size_t o = (size_t)(n0 + r) * K + k0 + tx;
    dhi[o] = hv;
    dlo[o] = f2bf(v - bf2f(hv));
  }
}

__global__ void k_split(const float* __restrict__ src, unsigned short* __restrict__ dhi,
                        unsigned short* __restrict__ dlo) {
  const size_t i = (size_t)blockIdx.x * 256 + threadIdx.x;
  const float4* p = reinterpret_cast<const float4*>(src) + i * 2;
  float4 a = p[0], b = p[1];
  float v[8] = {a.x, a.y, a.z, a.w, b.x, b.y, b.z, b.w};
  unsigned short hi[8], lo[8];
#pragma unroll
  for (int j = 0; j < 8; ++j) {
    hi[j] = f2bf(v[j]);
    lo[j] = f2bf(v[j] - bf2f(hi[j]));
  }
  uint4 oh, ol;
  oh.x = hi[0] | (hi[1] << 16); oh.y = hi[2] | (hi[3] << 16);
  oh.z = hi[4] | (hi[5] << 16); oh.w = hi[6] | (hi[7] << 16);
  ol.x = lo[0] | (lo[1] << 16); ol.y = lo[2] | (lo[3] << 16);
  ol.z = lo[4] | (lo[5] << 16); ol.w = lo[6] | (lo[7] << 16);
  reinterpret_cast<uint4*>(dhi)[i] = oh;
  reinterpret_cast<uint4*>(dlo)[i] = ol;
}

__global__ void k_emb2bf(const float* __restrict__ emb, unsigned short* __restrict__ ebf) {
  const size_t i = (size_t)blockIdx.x * 256 + threadIdx.x;
  const float4* p = reinterpret_cast<const float4*>(emb) + i * 2;
  float4 a = p[0], b = p[1];
  uint4 o;
  o.x = (unsigned)f2bf(a.x) | ((unsigned)f2bf(a.y) << 16);
  o.y = (unsigned)f2bf(a.z) | ((unsigned)f2bf(a.w) << 16);
  o.z = (unsigned)f2bf(b.x) | ((unsigned)f2bf(b.y) << 16);
  o.w = (unsigned)f2bf(b.z) | ((unsigned)f2bf(b.w) << 16);
  reinterpret_cast<uint4*>(ebf)[i] = o;
}

__global__ __launch_bounds__(256) void k_feat_mfma(
    const unsigned short* __restrict__ Ahi, const unsigned short* __restrict__ Alo,
    const unsigned short* __restrict__ Bhi, const unsigned short* __restrict__ Blo,
    const float* __restrict__ bias, float* __restrict__ femb) {
  const int m0 = blockIdx.x * 64, n0 = blockIdx.y * 64;
  const int tid = threadIdx.x, lane = tid & 63, w = tid >> 6;
  const int l15 = lane & 15, l4 = lane >> 4;
  f32x4 acc[4];
#pragma unroll
  for (int nt = 0; nt < 4; ++nt) acc[nt] = (f32x4){0.f, 0.f, 0.f, 0.f};
  const size_t arow = (size_t)(m0 + w * 16 + l15) * FEATN;
  for (int kk = 0; kk < FEATN / 32; ++kk) {
    const int k = kk * 32 + l4 * 8;
    bf16x8 a1 = *reinterpret_cast<const bf16x8*>(Ahi + arow + k);
    bf16x8 a2 = *reinterpret_cast<const bf16x8*>(Alo + arow + k);
#pragma unroll
    for (int nt = 0; nt < 4; ++nt) {
      const size_t brow = (size_t)(n0 + nt * 16 + l15) * FEATN + k;
      bf16x8 b1 = *reinterpret_cast<const bf16x8*>(Bhi + brow);
      bf16x8 b2 = *reinterpret_cast<const bf16x8*>(Blo + brow);
      acc[nt] = __builtin_amdgcn_mfma_f32_16x16x32_bf16(a1, b1, acc[nt], 0, 0, 0);
      acc[nt] = __builtin_amdgcn_mfma_f32_16x16x32_bf16(a1, b2, acc[nt], 0, 0, 0);
      acc[nt] = __builtin_amdgcn_mfma_f32_16x16x32_bf16(a2, b1, acc[nt], 0, 0, 0);
    }
  }
#pragma unroll
  for (int nt = 0; nt < 4; ++nt)
#pragma unroll
    for (int i = 0; i < 4; ++i) {
      int m = m0 + w * 16 + l4 * 4 + i, n = n0 + nt * 16 + l15;
      femb[(size_t)m * FHN + n] = tanhf(acc[nt][i] + bias[n]);
    }
}

__global__ void k_mean(const float* __restrict__ femb, float* __restrict__ fmean) {
  const int gid = blockIdx.x * 256 + threadIdx.x;  // 32768
  const int b = gid >> 9, f = gid & 511;
  float s = 0.f;
  for (int n = 0; n < NREG; ++n) s += femb[(size_t)(b * NREG + n) * FHN + f];
  fmean[gid] = s * (1.0f / NREG);
}

__global__ __launch_bounds__(256) void k_h0c0(const float* __restrict__ fmean,
    const float* __restrict__ Wc, const float* __restrict__ bc,
    const float* __restrict__ Wh, const float* __restrict__ bh,
    float* __restrict__ hbuf, float* __restrict__ cbuf,
    unsigned short* __restrict__ hshi, unsigned short* __restrict__ hslo) {
  const int n0 = blockIdx.x * 64, l = blockIdx.y, isH = blockIdx.z;
  const float* W   = (isH ? Wh : Wc) + (size_t)l * FHN * HID;
  const float* bias= (isH ? bh : bc) + l * HID;
  float* outp      = (isH ? hbuf : cbuf) + (size_t)l * BATCH * HID;
  __shared__ float As[16][68], Bs[16][68];
  const int tid = threadIdx.x, tx = tid & 15, ty = tid >> 4;
  float acc[4][4] = {};
  for (int k0 = 0; k0 < FHN; k0 += 16) {
#pragma unroll
    for (int e = 0; e < 4; ++e) { int idx = tid + e * 256, m = idx >> 4, k = idx & 15; As[k][m] = fmean[m * FHN + k0 + k]; }
#pragma unroll
    for (int e = 0; e < 4; ++e) { int idx = tid + e * 256, k = idx >> 6, n = idx & 63; Bs[k][n] = W[(size_t)(k0 + k) * HID + n0 + n]; }
    __syncthreads();
#pragma unroll
    for (int k = 0; k < 16; ++k) {
      float4 av = *(const float4*)&As[k][ty * 4];
      float4 bv = *(const float4*)&Bs[k][tx * 4];
      float a[4] = {av.x, av.y, av.z, av.w}, b[4] = {bv.x, bv.y, bv.z, bv.w};
#pragma unroll
      for (int i = 0; i < 4; ++i)
#pragma unroll
        for (int j = 0; j < 4; ++j) acc[i][j] = fmaf(a[i], b[j], acc[i][j]);
    }
    __syncthreads();
  }
#pragma unroll
  for (int i = 0; i < 4; ++i) {
    int m = ty * 4 + i, n = n0 + tx * 4;
    float vals[4];
#pragma unroll
    for (int j = 0; j < 4; ++j) vals[j] = acc[i][j] + bias[n + j];
    *(float4*)&outp[(size_t)m * HID + n] = make_float4(vals[0], vals[1], vals[2], vals[3]);
    if (isH) {
#pragma unroll
      for (int j = 0; j < 4; ++j) {
        unsigned short hv = f2bf(vals[j]);
        size_t o = (size_t)l * BATCH * HID + (size_t)m * HID + n + j;  // parity-0 slot
        hshi[o] = hv;
        hslo[o] = f2bf(vals[j] - bf2f(hv));
      }
    }
  }
}

__global__ void k_initx(unsigned short* __restrict__ xhi, unsigned short* __restrict__ xlo) {
  const int i = blockIdx.x * 256 + threadIdx.x;
  xhi[i] = 0x4040; xlo[i] = 0;      // 3.0 exact in bf16
}

// ================= per-step kernels =================

// ---- fused gates+cell (r6's proven device body as standalone kernel) ----
// 32 blocks x 1024 thr; block bl owns cols [bl*16, bl*16+16) of all 4 gates;
// wave w: gate g = w>>2, batch tile mt = w&3.
__global__ __launch_bounds__(1024) void k_lstm(
    const unsigned short* __restrict__ xh, const unsigned short* __restrict__ xl,
    const unsigned short* __restrict__ hh, const unsigned short* __restrict__ hl,
    const unsigned short* __restrict__ wih_hi, const unsigned short* __restrict__ wih_lo,
    const unsigned short* __restrict__ whh_hi, const unsigned short* __restrict__ whh_lo,
    const float* __restrict__ bias,            // [2048] this layer
    float* __restrict__ hbufl, float* __restrict__ cbufl,   // [64][512] f32 this layer
    unsigned short* __restrict__ ho_hi, unsigned short* __restrict__ ho_lo) {
  __shared__ float gs[4][64][16];
  const int bl = blockIdx.x, tid = threadIdx.x;
  const int lane = tid & 63, w = tid >> 6;
  const int l15 = lane & 15, l4 = lane >> 4;
  const int g = w >> 2, mt = w & 3;
  const size_t nrow = (size_t)(g * 512 + bl * 16 + l15) * 512;
  const size_t arow = (size_t)(mt * 16 + l15) * 512;
  f32x4 acc = (f32x4){0.f, 0.f, 0.f, 0.f};
#pragma unroll
  for (int ks = 0; ks < 16; ++ks) {          // x @ Wih (3-term bf16 split)
    const int k = ks * 32 + l4 * 8;
    bf16x8 b1 = *reinterpret_cast<const bf16x8*>(wih_hi + nrow + k);
    bf16x8 b2 = *reinterpret_cast<const bf16x8*>(wih_lo + nrow + k);
    bf16x8 a1 = *reinterpret_cast<const bf16x8*>(xh + arow + k);
    bf16x8 a2 = *reinterpret_cast<const bf16x8*>(xl + arow + k);
    acc = __builtin_amdgcn_mfma_f32_16x16x32_bf16(a1, b1, acc, 0, 0, 0);
    acc = __builtin_amdgcn_mfma_f32_16x16x32_bf16(a1, b2, acc, 0, 0, 0);
    acc = __builtin_amdgcn_mfma_f32_16x16x32_bf16(a2, b1, acc, 0, 0, 0);
  }
#pragma unroll
  for (int ks = 0; ks < 16; ++ks) {          // h @ Whh
    const int k = ks * 32 + l4 * 8;
    bf16x8 b1 = *reinterpret_cast<const bf16x8*>(whh_hi + nrow + k);
    bf16x8 b2 = *reinterpret_cast<const bf16x8*>(whh_lo + nrow + k);
    bf16x8 a1 = *reinterpret_cast<const bf16x8*>(hh + arow + k);
    bf16x8 a2 = *reinterpret_cast<const bf16x8*>(hl + arow + k);
    acc = __builtin_amdgcn_mfma_f32_16x16x32_bf16(a1, b1, acc, 0, 0, 0);
    acc = __builtin_amdgcn_mfma_f32_16x16x32_bf16(a1, b2, acc, 0, 0, 0);
    acc = __builtin_amdgcn_mfma_f32_16x16x32_bf16(a2, b1, acc, 0, 0, 0);
  }
#pragma unroll
  for (int i = 0; i < 4; ++i)
    gs[g][mt * 16 + l4 * 4 + i][l15] = acc[i];
  __syncthreads();
  {                                          // cell: 1024 threads = 64 b x 16 j
    const int b = tid >> 4, jl = tid & 15, j = bl * 16 + jl;
    float gi = gs[0][b][jl] + bias[j];
    float gf = gs[1][b][jl] + bias[512 + j];
    float gg = gs[2][b][jl] + bias[1024 + j];
    float go = gs[3][b][jl] + bias[1536 + j];
    const size_t o = (size_t)b * HID + j;
    float cn = sigm(gf) * cbufl[o] + sigm(gi) * tanhf(gg);
    float hn = sigm(go) * tanhf(cn);
    cbufl[o] = cn; hbufl[o] = hn;
    unsigned short hv = f2bf(hn);
    ho_hi[o] = hv; ho_lo[o] = f2bf(hn - bf2f(hv));
  }
}

// ---- logits (r3's proven kernel + nontemporal streaming loads) ----
__global__ __launch_bounds__(256) void k_logits(
    const unsigned short* __restrict__ embbf,   // [32000][512] bf16
    const unsigned short* __restrict__ h1bf,    // [64][512] bf16 (hi split of h1)
    const float* __restrict__ gum,              // [64][32000] (step slice)
    float* __restrict__ red) {
  const int v0 = blockIdx.x * 128;
  const int tid = threadIdx.x;
  const int lane = tid & 63, w = tid >> 6;
  const int l15 = lane & 15, l4 = lane >> 4;

  __shared__ unsigned short hl[32768];          // 64KB, [64][512] bf16, XOR-swizzled rows
  __shared__ float rm_[256], rs_[256], rv1_[256], rv2_[256];
  __shared__ int   ri1_[256], ri2_[256];

#pragma unroll
  for (int i = 0; i < 16; ++i) {
    int c = tid + i * 256;
    int row = c >> 6;
    int inb = (c & 63) << 4;
    uint4 v = *reinterpret_cast<const uint4*>(h1bf + ((size_t)c << 3));
    int sw = inb ^ ((row & 7) << 4);
    *reinterpret_cast<uint4*>(reinterpret_cast<char*>(hl) + row * 1024 + sw) = v;
  }
  __syncthreads();

  f32x4 acc[2][4];
#pragma unroll
  for (int m = 0; m < 2; ++m)
#pragma unroll
    for (int n = 0; n < 4; ++n) acc[m][n] = (f32x4){0.f, 0.f, 0.f, 0.f};

  const unsigned short* aptr = embbf + (size_t)(v0 + w * 32 + l15) * 512 + l4 * 8;
#pragma unroll
  for (int ks = 0; ks < 16; ++ks) {
    bf16x8 a0 = ntload_bf(aptr + ks * 32);
    bf16x8 a1 = ntload_bf(aptr + 16 * 512 + ks * 32);
    bf16x8 bb[4];
#pragma unroll
    for (int n = 0; n < 4; ++n) {
      int row = n * 16 + l15;
      int inb = ks * 64 + l4 * 16;
      int sw = inb ^ ((row & 7) << 4);
      bb[n] = *reinterpret_cast<const bf16x8*>(reinterpret_cast<const char*>(hl) + row * 1024 + sw);
    }
#pragma unroll
    for (int n = 0; n < 4; ++n) {
      acc[0][n] = __builtin_amdgcn_mfma_f32_16x16x32_bf16(a0, bb[n], acc[0][n], 0, 0, 0);
      acc[1][n] = __builtin_amdgcn_mfma_f32_16x16x32_bf16(a1, bb[n], acc[1][n], 0, 0, 0);
    }
  }

  const int vb = v0 + w * 32 + l4 * 4;
#pragma unroll
  for (int n = 0; n < 4; ++n) {
    const int b = n * 16 + l15;
    const float* gb = gum + (size_t)b * VOC + vb;
    f32x4 g0 = ntload_f4(gb);
    f32x4 g1 = ntload_f4(gb + 16);
    float lg[8] = {acc[0][n][0], acc[0][n][1], acc[0][n][2], acc[0][n][3],
                   acc[1][n][0], acc[1][n][1], acc[1][n][2], acc[1][n][3]};
    float gv[8] = {g0[0], g0[1], g0[2], g0[3], g1[0], g1[1], g1[2], g1[3]};
    float mx = lg[0];
#pragma unroll
    for (int i = 1; i < 8; ++i) mx = fmaxf(mx, lg[i]);
    float ss = 0.f;
    float v1 = -INFINITY, v2 = -INFINITY; int i1 = 0x7fffffff, i2 = 0x7fffffff;
#pragma unroll
    for (int i = 0; i < 8; ++i) {
      ss += expf(lg[i] - mx);
      float val = lg[i] + gv[i];
      int idx = vb + (i & 3) + ((i >> 2) << 4);
      if (better(val, idx, v1, i1)) { v2 = v1; i2 = i1; v1 = val; i1 = idx; }
      else if (better(val, idx, v2, i2)) { v2 = val; i2 = idx; }
    }
#pragma unroll
    for (int mask = 16; mask <= 32; mask <<= 1) {
      float om = __shfl_xor(mx, mask);
      float os = __shfl_xor(ss, mask);
      float u1 = __shfl_xor(v1, mask); int j1 = __shfl_xor(i1, mask);
      float u2 = __shfl_xor(v2, mask); int j2 = __shfl_xor(i2, mask);
      lse_merge(mx, ss, om, os);
      top2_merge(v1, i1, v2, i2, u1, j1, u2, j2);
    }
    if (lane < 16) {
      int slot = (w * 4 + n) * 16 + l15;
      rm_[slot] = mx; rs_[slot] = ss;
      rv1_[slot] = v1; ri1_[slot] = i1; rv2_[slot] = v2; ri2_[slot] = i2;
    }
  }
  __syncthreads();
  if (tid < 64) {
    const int n = tid >> 4, c = tid & 15;
    int s0 = n * 16 + c;
    float M = rm_[s0], S = rs_[s0], V1 = rv1_[s0], V2 = rv2_[s0];
    int I1 = ri1_[s0], I2 = ri2_[s0];
#pragma unroll
    for (int ww = 1; ww < 4; ++ww) {
      int sl = (ww * 4 + n) * 16 + c;
      lse_merge(M, S, rm_[sl], rs_[sl]);
      top2_merge(V1, I1, V2, I2, rv1_[sl], ri1_[sl], rv2_[sl], ri2_[sl]);
    }
    float* rp = red + ((size_t)blockIdx.x * 64 + tid) * 8;
    rp[0] = M; rp[1] = S;
    rp[2] = V1; rp[3] = __int_as_float(I1);
    rp[4] = V2; rp[5] = __int_as_float(I2);
  }
}

// ---- final reduce + exact f32 rescore + sample (r3's proven kernel) ----
__global__ __launch_bounds__(256) void k_sample(const float* __restrict__ red,
    const float* __restrict__ emb, const float* __restrict__ h1f, const float* __restrict__ gum,
    unsigned short* __restrict__ xhi, unsigned short* __restrict__ xlo,
    float* __restrict__ out, int t) {
  const int b = blockIdx.x, tid = threadIdx.x;
  __shared__ float rm[256], rs[256], rv1[256], rv2[256];
  __shared__ int   ri1[256], ri2[256];
  float m = -INFINITY, s = 0.f, v1 = -INFINITY, v2 = -INFINITY;
  int i1 = 0x7fffffff, i2 = 0x7fffffff;
  if (tid < NVT) {
    const float* rp = red + ((size_t)tid * 64 + b) * 8;
    m = rp[0]; s = rp[1];
    v1 = rp[2]; i1 = __float_as_int(rp[3]);
    v2 = rp[4]; i2 = __float_as_int(rp[5]);
  }
  rm[tid] = m; rs[tid] = s; rv1[tid] = v1; ri1[tid] = i1; rv2[tid] = v2; ri2[tid] = i2;
  __syncthreads();
  for (int off = 128; off > 0; off >>= 1) {
    if (tid < off) {
      float M = rm[tid], S = rs[tid];
      lse_merge(M, S, rm[tid + off], rs[tid + off]);
      rm[tid] = M; rs[tid] = S;
      float a1 = rv1[tid], a2 = rv2[tid]; int c1 = ri1[tid], c2 = ri2[tid];
      top2_merge(a1, c1, a2, c2, rv1[tid + off], ri1[tid + off], rv2[tid + off], ri2[tid + off]);
      rv1[tid] = a1; ri1[tid] = c1; rv2[tid] = a2; ri2[tid] = c2;
    }
    __syncthreads();
  }
  const int I1 = ri1[0], I2 = ri2[0];
  const float lse = rm[0] + logf(rs[0]);
  __shared__ float s1[256], s2[256];
  const float* e1 = emb + (size_t)I1 * EMBN;
  const float* e2 = emb + (size_t)I2 * EMBN;
  const float* hb = h1f + b * EMBN;
  float d1 = 0.f, d2 = 0.f;
  for (int k = tid; k < EMBN; k += 256) {
    float hv = hb[k];
    d1 = fmaf(e1[k], hv, d1);
    d2 = fmaf(e2[k], hv, d2);
  }
  s1[tid] = d1; s2[tid] = d2;
  __syncthreads();
  for (int off = 128; off > 0; off >>= 1) {
    if (tid < off) { s1[tid] += s1[tid + off]; s2[tid] += s2[tid + off]; }
    __syncthreads();
  }
  const float x1 = s1[0] + gum[(size_t)b * VOC + I1];
  const float x2 = s2[0] + gum[(size_t)b * VOC + I2];
  int tok; float dsel;
  if (x2 > x1 || (x2 == x1 && I2 < I1)) { tok = I2; dsel = s2[0]; }
  else                                  { tok = I1; dsel = s1[0]; }
  const float* et = emb + (size_t)tok * EMBN;
  for (int k = tid; k < EMBN; k += 256) {
    float ev = et[k];
    unsigned short hv = f2bf(ev);
    xhi[b * EMBN + k] = hv;
    xlo[b * EMBN + k] = f2bf(ev - bf2f(hv));
  }
  if (tid == 0) {
    out[b * TSTEPS + t] = (float)tok;
    out[BATCH * TSTEPS + b * TSTEPS + t] = dsel - lse;
  }
}

}  // namespace

extern "C" void kernel_launch(void* const* d_in, const int* in_sizes, int n_in,
                              void* d_out, int out_size, void* d_ws, size_t ws_size,
                              hipStream_t stream) {
  const float* img  = (const float*)d_in[0];
  const float* W_fh = (const float*)d_in[1];
  const float* b_fh = (const float*)d_in[2];
  const float* Wc   = (const float*)d_in[3];
  const float* bc   = (const float*)d_in[4];
  const float* Wh   = (const float*)d_in[5];
  const float* bh   = (const float*)d_in[6];
  const float* W_ih = (const float*)d_in[7];
  const float* W_hh = (const float*)d_in[8];
  const float* b_l  = (const float*)d_in[9];
  const float* emb  = (const float*)d_in[10];
  const float* gum  = (const float*)d_in[11];
  float* out = (float*)d_out;

  float* w     = (float*)d_ws;
  float* femb  = w;                                    // 3136*512
  float* fmean = femb + (size_t)3136 * 512;            // 64*512
  float* hbuf  = fmean + 64 * 512;                     // [2 layer][64*512] f32
  float* cbuf  = hbuf + 2 * 64 * 512;                  // [2 layer][64*512] f32
  float* red   = cbuf + 2 * 64 * 512;                  // 250*64*8

  unsigned short* us = (unsigned short*)(red + 250 * 64 * 8);
  unsigned short* embbf  = us;                                  // 32000*512
  unsigned short* imghi  = embbf + (size_t)VOC * EMBN;          // 3136*2048
  unsigned short* imglo  = imghi + (size_t)3136 * 2048;
  unsigned short* wfh_hi = imglo + (size_t)3136 * 2048;         // 512*2048 (W_fh^T)
  unsigned short* wfh_lo = wfh_hi + (size_t)512 * 2048;
  unsigned short* wg     = wfh_lo + (size_t)512 * 2048;         // [l][mat][hi/lo][2048][512]
  const size_t WGM = (size_t)G4 * 512;
  unsigned short* xhi    = wg + 8 * WGM;                        // 64*512
  unsigned short* xlo    = xhi + 64 * 512;
  unsigned short* hshi   = xlo + 64 * 512;                      // [2 parity][2 layer][64][512]
  unsigned short* hslo   = hshi + (size_t)4 * 64 * 512;

  auto wgp = [&](int l, int mat, int part_) -> unsigned short* {
    return wg + (((size_t)l * 2 + mat) * 2 + part_) * WGM;
  };
  const size_t HS = (size_t)BATCH * HID;
  auto hs_hi = [&](int par, int l) { return hshi + ((size_t)par * 2 + l) * HS; };
  auto hs_lo = [&](int par, int l) { return hslo + ((size_t)par * 2 + l) * HS; };

  // ---- one-time prep ----
  k_emb2bf<<<8000, 256, 0, stream>>>(emb, embbf);
  k_split<<<3136 * 2048 / 8 / 256, 256, 0, stream>>>(img, imghi, imglo);
  k_trans<<<dim3(FEATN / 32, FHN / 32), 256, 0, stream>>>(W_fh, wfh_hi, wfh_lo, FEATN, FHN);
  for (int l = 0; l < 2; ++l) {
    k_trans<<<dim3(EMBN / 32, G4 / 32), 256, 0, stream>>>(W_ih + (size_t)l * EMBN * G4, wgp(l, 0, 0), wgp(l, 0, 1), EMBN, G4);
    k_trans<<<dim3(HID / 32, G4 / 32), 256, 0, stream>>>(W_hh + (size_t)l * HID * G4, wgp(l, 1, 0), wgp(l, 1, 1), HID, G4);
  }
  k_feat_mfma<<<dim3(49, 8), 256, 0, stream>>>(imghi, imglo, wfh_hi, wfh_lo, b_fh, femb);
  k_mean<<<128, 256, 0, stream>>>(femb, fmean);
  k_h0c0<<<dim3(8, 2, 2), 256, 0, stream>>>(fmean, Wc, bc, Wh, bh, hbuf, cbuf, hshi, hslo);
  k_initx<<<128, 256, 0, stream>>>(xhi, xlo);

  // ---- 40-step decode: 4 launches/step, all dependencies via kernel boundaries ----
  for (int t = 0; t < TSTEPS; ++t) {
    const float* gum_t = gum + (size_t)t * BATCH * VOC;
    const int p = t & 1, q = p ^ 1;
    // layer 0: x, h0[p] -> h0[q]
    k_lstm<<<32, 1024, 0, stream>>>(xhi, xlo, hs_hi(p, 0), hs_lo(p, 0),
        wgp(0, 0, 0), wgp(0, 0, 1), wgp(0, 1, 0), wgp(0, 1, 1),
        b_l, hbuf, cbuf, hs_hi(q, 0), hs_lo(q, 0));
    // layer 1: h0[q], h1[p] -> h1[q]
    k_lstm<<<32, 1024, 0, stream>>>(hs_hi(q, 0), hs_lo(q, 0), hs_hi(p, 1), hs_lo(p, 1),
        wgp(1, 0, 0), wgp(1, 0, 1), wgp(1, 1, 0), wgp(1, 1, 1),
        b_l + 2048, hbuf + HS, cbuf + HS, hs_hi(q, 1), hs_lo(q, 1));
    // logits + LSE + top-2 screening (NT streaming loads)
    k_logits<<<NVT, 256, 0, stream>>>(embbf, hs_hi(q, 1), gum_t, red);
    // final reduce + exact rescore + sample (+ next-x split emit)
    k_sample<<<64, 256, 0, stream>>>(red, emb, hbuf + HS, gum_t, xhi, xlo, out, t);
  }
}